// Round 3
// baseline (148254.077 us; speedup 1.0000x reference)
//
#include <hip/hip_runtime.h>
#include <cstdint>

#define HH 384
#define TTC 32
#define NBINS 256

__device__ inline float4 ld4(const float* p){ return *(const float4*)p; }

// ---------------- pos = cumsum(x[...,0]!=0) * mask ----------------
__global__ __launch_bounds__(1024) void pos_kernel(const float* __restrict__ x,
    int* __restrict__ pos, int T)
{
  __shared__ int s[1024];
  int b = blockIdx.x, tid = threadIdx.x;
  int m = 0;
  if (tid < T) m = (x[((size_t)b*T + tid)*HH] != 0.f) ? 1 : 0;
  s[tid] = m;
  __syncthreads();
  for (int off = 1; off < 1024; off <<= 1){
    int add = (tid >= off) ? s[tid-off] : 0;
    __syncthreads();
    s[tid] += add;
    __syncthreads();
  }
  if (tid < T) pos[(size_t)b*T + tid] = s[tid] * m;
}

// ---------------- out = x + alpha * sinusoidal_pe(pos) ----------------
__global__ __launch_bounds__(HH) void add_pe_kernel(const float* __restrict__ x,
    const int* __restrict__ pos, const float* __restrict__ alpha,
    float* __restrict__ out)
{
  int row = blockIdx.x; int i = threadIdx.x;
  int p = pos[row];
  float pe = 0.f;
  if (p != 0){
    int j = (i < HH/2) ? i : i - HH/2;
    float inv = expf((float)j * -0.04822167734018944f); // -ln(10000)/191
    float ang = (float)p * inv;
    pe = (i < HH/2) ? sinf(ang) : cosf(ang);
  }
  out[(size_t)row*HH + i] = x[(size_t)row*HH + i] + alpha[0]*pe;
}

// ---------------- fused conv1d(same,K) + relu + LN(channels) + affine ----------------
// One block = 32 time-steps x 384 output channels. Input tile staged in LDS
// (broadcast ds_read_b128). Weights double-buffered in registers (prefetch
// quad i0+4 while computing i0); xs reads pipelined 3 deep.
template<int K>
__global__ __launch_bounds__(HH, 3) void conv_ln_kernel(
    const float* __restrict__ in, const float* __restrict__ w,
    const float* __restrict__ bias, const float* __restrict__ g,
    const float* __restrict__ be, float* __restrict__ out, int T)
{
  constexpr int P = (K-1)/2;
  constexpr int R = TTC + K - 1;
  __shared__ float xs[R][HH];
  __shared__ float ps[6][TTC];
  __shared__ float pq[6][TTC];

  int ntile = T / TTC;
  int b  = blockIdx.x / ntile;
  int t0 = (blockIdx.x % ntile) * TTC;
  int o  = threadIdx.x;
  const float* inb = in + (size_t)b*T*HH;

  #pragma unroll
  for (int r = 0; r < R; ++r){
    int t = t0 + r - P;
    xs[r][o] = (t >= 0 && t < T) ? inb[(size_t)t*HH + o] : 0.f;
  }
  __syncthreads();

  float acc[TTC];
  float bo = bias[o];
  #pragma unroll
  for (int t = 0; t < TTC; ++t) acc[t] = bo;

  const float* wrow = w + (size_t)o*HH*K;
  float wA[4*K], wB[4*K];
  #pragma unroll
  for (int q = 0; q < K; ++q) *(float4*)(wA + 4*q) = ld4(wrow + 4*q);

#define COMPUTE_QUAD(WR, I0)                                                  \
  do {                                                                        \
    float4 xp0 = ld4(&xs[0][(I0)]);                                           \
    float4 xp1 = ld4(&xs[1][(I0)]);                                           \
    float4 xp2 = ld4(&xs[2][(I0)]);                                           \
    _Pragma("unroll")                                                         \
    for (int r = 0; r < R; ++r){                                              \
      float4 xc = xp0; xp0 = xp1; xp1 = xp2;                                  \
      if (r + 3 < R) xp2 = ld4(&xs[r+3][(I0)]);                               \
      float xa[4] = {xc.x, xc.y, xc.z, xc.w};                                 \
      _Pragma("unroll")                                                       \
      for (int di = 0; di < 4; ++di){                                         \
        _Pragma("unroll")                                                     \
        for (int k = 0; k < K; ++k){                                          \
          int tt = r - k;                                                     \
          if (tt >= 0 && tt < TTC)                                            \
            acc[tt] = fmaf(xa[di], (WR)[di*K + k], acc[tt]);                  \
        }                                                                     \
      }                                                                       \
    }                                                                         \
  } while (0)

  for (int i0 = 0; i0 < HH; i0 += 8){
    { // prefetch quad i0+4 into wB
      const float* wp = wrow + (size_t)(i0 + 4)*K;
      #pragma unroll
      for (int q = 0; q < K; ++q) *(float4*)(wB + 4*q) = ld4(wp + 4*q);
    }
    COMPUTE_QUAD(wA, i0);
    { // prefetch quad i0+8 into wA (last iter harmlessly reloads quad 0)
      int nx = (i0 + 8 < HH) ? (i0 + 8) : 0;
      const float* wp = wrow + (size_t)nx*K;
      #pragma unroll
      for (int q = 0; q < K; ++q) *(float4*)(wA + 4*q) = ld4(wp + 4*q);
    }
    COMPUTE_QUAD(wB, i0 + 4);
  }
#undef COMPUTE_QUAD

  // relu
  #pragma unroll
  for (int t = 0; t < TTC; ++t) acc[t] = fmaxf(acc[t], 0.f);

  // LN over channels (across the 384 threads), per t
  int wid = threadIdx.x >> 6, lane = threadIdx.x & 63;
  #pragma unroll
  for (int t = 0; t < TTC; ++t){
    float s1 = acc[t], s2 = acc[t]*acc[t];
    #pragma unroll
    for (int off = 32; off; off >>= 1){
      s1 += __shfl_xor(s1, off);
      s2 += __shfl_xor(s2, off);
    }
    if (lane == 0){ ps[wid][t] = s1; pq[wid][t] = s2; }
  }
  __syncthreads();

  float gg = g[o], bb = be[o];
  #pragma unroll
  for (int t = 0; t < TTC; ++t){
    float s1 = 0.f, s2 = 0.f;
    #pragma unroll
    for (int ww = 0; ww < 6; ++ww){ s1 += ps[ww][t]; s2 += pq[ww][t]; }
    float m   = s1 * (1.f/HH);
    float var = fmaxf(s2 * (1.f/HH) - m*m, 0.f);
    float rr  = rsqrtf(var + 1e-5f);
    out[((size_t)b*T + t0 + t)*HH + o] = (acc[t] - m)*rr*gg + bb;
  }
}

// ---------------- pred = h @ lw + lb ; idx = searchsorted(bins, pred, 'left') ----------------
__global__ __launch_bounds__(256) void proj_var_kernel(const float* __restrict__ h,
    const float* __restrict__ lw, const float* __restrict__ lb,
    const float* __restrict__ bins, float* __restrict__ pred,
    int* __restrict__ idx, int nrows)
{
  int lane = threadIdx.x & 63, wid = threadIdx.x >> 6;
  int wave = blockIdx.x*4 + wid, nw = gridDim.x*4;
  float lwr[6];
  #pragma unroll
  for (int j = 0; j < 6; ++j) lwr[j] = lw[lane + 64*j];
  float lbv = lb[0];
  for (int row = wave; row < nrows; row += nw){
    const float* hr = h + (size_t)row*HH;
    float s = 0.f;
    #pragma unroll
    for (int j = 0; j < 6; ++j) s = fmaf(hr[lane + 64*j], lwr[j], s);
    #pragma unroll
    for (int off = 32; off; off >>= 1) s += __shfl_xor(s, off);
    if (lane == 0){
      float v = s + lbv;
      pred[row] = v;
      int lo = 0, hi = NBINS - 1;
      while (lo < hi){ int mid = (lo + hi) >> 1; if (bins[mid] < v) lo = mid + 1; else hi = mid; }
      idx[row] = lo;
    }
  }
}

// ---------------- log_d, dur (float), dur (int) ----------------
__global__ __launch_bounds__(256) void proj_dur_kernel(const float* __restrict__ h,
    const float* __restrict__ lw, const float* __restrict__ lb,
    const unsigned char* __restrict__ mask, float* __restrict__ logd,
    float* __restrict__ durf, int* __restrict__ duri, int nrows)
{
  int lane = threadIdx.x & 63, wid = threadIdx.x >> 6;
  int wave = blockIdx.x*4 + wid, nw = gridDim.x*4;
  float lwr[6];
  #pragma unroll
  for (int j = 0; j < 6; ++j) lwr[j] = lw[lane + 64*j];
  float lbv = lb[0];
  for (int row = wave; row < nrows; row += nw){
    const float* hr = h + (size_t)row*HH;
    float s = 0.f;
    #pragma unroll
    for (int j = 0; j < 6; ++j) s = fmaf(hr[lane + 64*j], lwr[j], s);
    #pragma unroll
    for (int off = 32; off; off >>= 1) s += __shfl_xor(s, off);
    if (lane == 0){
      float v = s + lbv;
      if (mask[row]) v = 0.f;
      logd[row] = v;
      float d = fmaxf(rintf(expf(v) - 1.f), 0.f);
      durf[row] = d;
      duri[row] = (int)d;
    }
  }
}

// ---------------- per-batch inclusive cumsum of dur, mel_len ----------------
__global__ __launch_bounds__(1024) void cumsum_kernel(const int* __restrict__ duri,
    int* __restrict__ cum, float* __restrict__ mel, int T, int ML)
{
  __shared__ int s[1024];
  int b = blockIdx.x, tid = threadIdx.x;
  s[tid] = (tid < T) ? duri[(size_t)b*T + tid] : 0;
  __syncthreads();
  for (int off = 1; off < 1024; off <<= 1){
    int add = (tid >= off) ? s[tid-off] : 0;
    __syncthreads();
    s[tid] += add;
    __syncthreads();
  }
  if (tid < T) cum[(size_t)b*T + tid] = s[tid];
  if (tid == T-1) mel[b] = (float)min(s[tid], ML);
}

// ---------------- x_adapt = x + pitch_table[ip] + energy_table[ie] ----------------
__global__ __launch_bounds__(256) void xadapt_kernel(const float* __restrict__ x,
    const int* __restrict__ ip, const int* __restrict__ ie,
    const float* __restrict__ pt, const float* __restrict__ et,
    float* __restrict__ xa, int nrows)
{
  int gid = blockIdx.x*256 + threadIdx.x;
  int n4 = nrows * (HH/4);
  if (gid >= n4) return;
  int row = gid / (HH/4);
  int c = gid - row*(HH/4);
  float4 xv = ((const float4*)x)[gid];
  const float4* pr = (const float4*)(pt + (size_t)ip[row]*HH);
  const float4* er = (const float4*)(et + (size_t)ie[row]*HH);
  float4 pv = pr[c], ev = er[c];
  ((float4*)xa)[gid] = make_float4(xv.x+pv.x+ev.x, xv.y+pv.y+ev.y,
                                   xv.z+pv.z+ev.z, xv.w+pv.w+ev.w);
}

// ---------------- length regulate: gather + zero-fill ----------------
__global__ __launch_bounds__(256) void lr_kernel(const float* __restrict__ xa,
    const int* __restrict__ cum, float* __restrict__ out, int T, int ML)
{
  constexpr int FR = 32;
  __shared__ int scum[1024];
  __shared__ int sidx[FR];
  __shared__ int svalid[FR];
  int b  = blockIdx.y;
  int f0 = blockIdx.x * FR;
  for (int i = threadIdx.x; i < T; i += 256) scum[i] = cum[(size_t)b*T + i];
  __syncthreads();
  int total = scum[T-1];
  if (threadIdx.x < FR){
    int f = f0 + threadIdx.x;
    int lo = 0, hi = T;
    while (lo < hi){ int mid = (lo + hi) >> 1; if (scum[mid] <= f) lo = mid + 1; else hi = mid; }
    sidx[threadIdx.x] = min(lo, T-1);
    svalid[threadIdx.x] = (f < total) ? 1 : 0;
  }
  __syncthreads();
  #pragma unroll
  for (int it = 0; it < FR*(HH/4)/256; ++it){
    int item = it*256 + threadIdx.x;
    int fl = item / (HH/4);
    int c  = item - fl*(HH/4);
    int f  = f0 + fl;
    if (f >= ML) continue;
    float4 v = make_float4(0.f,0.f,0.f,0.f);
    if (svalid[fl]) v = ((const float4*)(xa + ((size_t)b*T + sidx[fl])*HH))[c];
    ((float4*)(out + ((size_t)b*ML + f)*HH))[c] = v;
  }
}

extern "C" void kernel_launch(void* const* d_in, const int* in_sizes, int n_in,
                              void* d_out, int out_size, void* d_ws, size_t ws_size,
                              hipStream_t stream)
{
  const float* x        = (const float*)d_in[0];
  const unsigned char* src_mask = (const unsigned char*)d_in[2];
  const float* dp_w1 = (const float*)d_in[4];
  const float* dp_b1 = (const float*)d_in[5];
  const float* dp_g1 = (const float*)d_in[6];
  const float* dp_be1= (const float*)d_in[7];
  const float* dp_w2 = (const float*)d_in[8];
  const float* dp_b2 = (const float*)d_in[9];
  const float* dp_g2 = (const float*)d_in[10];
  const float* dp_be2= (const float*)d_in[11];
  const float* dp_lw = (const float*)d_in[12];
  const float* dp_lb = (const float*)d_in[13];
  const float* pp_cw = (const float*)d_in[14];
  const float* pp_cb = (const float*)d_in[15];
  const float* pp_g  = (const float*)d_in[16];
  const float* pp_b  = (const float*)d_in[17];
  const float* pp_lw = (const float*)d_in[18];
  const float* pp_lb = (const float*)d_in[19];
  const float* pp_alpha = (const float*)d_in[20];
  const float* ep_cw = (const float*)d_in[21];
  const float* ep_cb = (const float*)d_in[22];
  const float* ep_g  = (const float*)d_in[23];
  const float* ep_b  = (const float*)d_in[24];
  const float* ep_lw = (const float*)d_in[25];
  const float* ep_lb = (const float*)d_in[26];
  const float* ep_alpha = (const float*)d_in[27];
  const float* pbins = (const float*)d_in[28];
  const float* ebins = (const float*)d_in[29];
  const float* ptab  = (const float*)d_in[30];
  const float* etab  = (const float*)d_in[31];

  int B = in_sizes[1];
  int T = in_sizes[0] / (B*HH);
  int ML = (int)(((long long)out_size - B - 4LL*B*T) / ((long long)B*HH));
  size_t rows = (size_t)B*T;

  float* bufA = (float*)d_ws;
  float* bufB = bufA + rows*HH;
  int* pos    = (int*)(bufB + rows*HH);
  int* idx_p  = pos + rows;
  int* idx_e  = idx_p + rows;
  int* dur_i  = idx_e + rows;
  int* cum    = dur_i + rows;

  float* out0    = (float*)d_out;
  float* logd    = out0 + (size_t)B*ML*HH;
  float* durf    = logd + rows;
  float* pitchp  = durf + rows;
  float* energyp = pitchp + rows;
  float* mel     = energyp + rows;

  int conv_grid = B * (T / TTC);

  pos_kernel<<<B, 1024, 0, stream>>>(x, pos, T);

  // ---- pitch predictor: 5 conv layers ----
  add_pe_kernel<<<(int)rows, HH, 0, stream>>>(x, pos, pp_alpha, bufA);
  {
    float* src = bufA; float* dst = bufB;
    for (int l = 0; l < 5; ++l){
      conv_ln_kernel<5><<<conv_grid, HH, 0, stream>>>(src,
          pp_cw + (size_t)l*HH*HH*5, pp_cb + (size_t)l*HH,
          pp_g + (size_t)l*HH, pp_b + (size_t)l*HH, dst, T);
      float* t2 = dst; dst = src; src = t2;
    }
    proj_var_kernel<<<256, 256, 0, stream>>>(src, pp_lw, pp_lb, pbins,
                                             pitchp, idx_p, (int)rows);
  }

  // ---- energy predictor: 2 conv layers ----
  add_pe_kernel<<<(int)rows, HH, 0, stream>>>(x, pos, ep_alpha, bufA);
  {
    float* src = bufA; float* dst = bufB;
    for (int l = 0; l < 2; ++l){
      conv_ln_kernel<5><<<conv_grid, HH, 0, stream>>>(src,
          ep_cw + (size_t)l*HH*HH*5, ep_cb + (size_t)l*HH,
          ep_g + (size_t)l*HH, ep_b + (size_t)l*HH, dst, T);
      float* t2 = dst; dst = src; src = t2;
    }
    proj_var_kernel<<<256, 256, 0, stream>>>(src, ep_lw, ep_lb, ebins,
                                             energyp, idx_e, (int)rows);
  }

  // ---- duration predictor: 2 conv layers (k=3) ----
  conv_ln_kernel<3><<<conv_grid, HH, 0, stream>>>(x, dp_w1, dp_b1, dp_g1, dp_be1, bufB, T);
  conv_ln_kernel<3><<<conv_grid, HH, 0, stream>>>(bufB, dp_w2, dp_b2, dp_g2, dp_be2, bufA, T);
  proj_dur_kernel<<<256, 256, 0, stream>>>(bufA, dp_lw, dp_lb, src_mask,
                                           logd, durf, dur_i, (int)rows);

  cumsum_kernel<<<B, 1024, 0, stream>>>(dur_i, cum, mel, T, ML);

  xadapt_kernel<<<(int)((rows*(HH/4) + 255)/256), 256, 0, stream>>>(
      x, idx_p, idx_e, ptab, etab, bufB, (int)rows);

  lr_kernel<<<dim3(ML/32, B), 256, 0, stream>>>(bufB, cum, out0, T, ML);
}

// Round 4
// 1719.334 us; speedup vs baseline: 86.2276x; 86.2276x over previous
//
#include <hip/hip_runtime.h>
#include <cstdint>

#define HH 384
#define NBINS 256

typedef __attribute__((ext_vector_type(8))) short short8v;
typedef __attribute__((ext_vector_type(4))) float float4v;

__device__ inline float4 ld4(const float* p){ return *(const float4*)p; }

__device__ inline unsigned short bf16_rne(float f){
  unsigned u = __float_as_uint(f);
  unsigned r = u + 0x7FFFu + ((u >> 16) & 1u);
  return (unsigned short)(r >> 16);
}
__device__ inline float bf16_to_f(unsigned short h){
  return __uint_as_float(((unsigned)h) << 16);
}

// ---------------- pos = cumsum(x[...,0]!=0) * mask ----------------
__global__ __launch_bounds__(1024) void pos_kernel(const float* __restrict__ x,
    int* __restrict__ pos, int T)
{
  __shared__ int s[1024];
  int b = blockIdx.x, tid = threadIdx.x;
  int m = 0;
  if (tid < T) m = (x[((size_t)b*T + tid)*HH] != 0.f) ? 1 : 0;
  s[tid] = m;
  __syncthreads();
  for (int off = 1; off < 1024; off <<= 1){
    int add = (tid >= off) ? s[tid-off] : 0;
    __syncthreads();
    s[tid] += add;
    __syncthreads();
  }
  if (tid < T) pos[(size_t)b*T + tid] = s[tid] * m;
}

// ---------------- out = x + alpha * sinusoidal_pe(pos) ----------------
__global__ __launch_bounds__(HH) void add_pe_kernel(const float* __restrict__ x,
    const int* __restrict__ pos, const float* __restrict__ alpha,
    float* __restrict__ out)
{
  int row = blockIdx.x; int i = threadIdx.x;
  int p = pos[row];
  float pe = 0.f;
  if (p != 0){
    int j = (i < HH/2) ? i : i - HH/2;
    float inv = expf((float)j * -0.04822167734018944f); // -ln(10000)/191
    float ang = (float)p * inv;
    pe = (i < HH/2) ? sinf(ang) : cosf(ang);
  }
  out[(size_t)row*HH + i] = x[(size_t)row*HH + i] + alpha[0]*pe;
}

// ---------------- weight transform: w[o][i][k] f32 -> B-fragment bf16 hi/lo ----
// Layout: [s][jg][o(384)][jj(8)], s = k*12 + (i>>5), jg=(i>>3)&3, jj=i&7
template<int K>
__global__ __launch_bounds__(256) void wtrans_kernel(const float* __restrict__ w,
    unsigned short* __restrict__ whi, unsigned short* __restrict__ wlo)
{
  int gid = blockIdx.x*256 + threadIdx.x; // over 384*384 (o,i)
  if (gid >= 384*384) return;
  int o = gid / 384, i = gid - (gid/384)*384;
  int c = i >> 5, jg = (i >> 3) & 3, jj = i & 7;
  #pragma unroll
  for (int k = 0; k < K; ++k){
    float v = w[((size_t)o*384 + i)*K + k];
    unsigned short hi = bf16_rne(v);
    float lf = v - bf16_to_f(hi);
    unsigned short lo = bf16_rne(lf);
    int s = k*12 + c;
    size_t dst = ((size_t)(s*4 + jg)*384 + o)*8 + jj;
    whi[dst] = hi; wlo[dst] = lo;
  }
}

// ---------------- fused conv1d(same,K)+relu+LN via bf16-split MFMA ----------------
// Block: 32 timesteps x 384 out-channels, 4 waves (wave w -> o in [w*96, w*96+96)).
// K-dim = 384*K (kk = k*384 + i), 12*K steps of 32. acc fp32 via 3-term split:
// xh*wh + xh*wl + xl*wh  (error ~1e-5 rel, comparable to fp32 reorder noise).
template<int K>
__global__ __launch_bounds__(256) void conv_mfma_kernel(
    const float* __restrict__ in, const unsigned short* __restrict__ whi,
    const unsigned short* __restrict__ wlo, const float* __restrict__ bias,
    const float* __restrict__ g, const float* __restrict__ be,
    float* __restrict__ out, int T)
{
  constexpr int M  = 32;
  constexpr int P  = (K-1)/2;
  constexpr int RT = M + K - 1;
  constexpr int NS = 12*K;
  constexpr int LDP = 392;        // pad: 784B row stride -> 16B-aligned, 2-way banks
  __shared__ unsigned short xs_hi[RT*LDP];
  __shared__ unsigned short xs_lo[RT*LDP];
  __shared__ float ps[4][M], pq[4][M];

  int ntile = T / M;
  int b  = blockIdx.x / ntile;
  int t0 = (blockIdx.x % ntile) * M;
  int tid = threadIdx.x;
  const float* inb = in + (size_t)b*T*HH;

  // stage input tile, converting f32 -> bf16 hi/lo
  for (int e = tid; e < RT*384; e += 256){
    int r = e / 384, col = e - (e/384)*384;
    int t = t0 + r - P;
    float v = (t >= 0 && t < T) ? inb[(size_t)t*HH + col] : 0.f;
    unsigned short h = bf16_rne(v);
    float lf = v - bf16_to_f(h);
    xs_hi[r*LDP + col] = h;
    xs_lo[r*LDP + col] = bf16_rne(lf);
  }
  __syncthreads();

  int wv = tid >> 6, ln = tid & 63;
  int l15 = ln & 15, lg = ln >> 4;
  int o0 = wv * 96;

  const unsigned short* bh = whi + ((size_t)lg*384 + o0 + l15)*8;
  const unsigned short* bl = wlo + ((size_t)lg*384 + o0 + l15)*8;
  int a_base = l15*LDP + lg*8;

  float4v acc[2][6];
  #pragma unroll
  for (int nt = 0; nt < 6; ++nt){
    float bv = bias[o0 + nt*16 + l15];
    acc[0][nt] = (float4v){bv,bv,bv,bv};
    acc[1][nt] = (float4v){bv,bv,bv,bv};
  }

  short8v BAh[6], BAl[6], BBh[6], BBl[6];
  #pragma unroll
  for (int nt = 0; nt < 6; ++nt){
    BAh[nt] = *(const short8v*)(bh + nt*128);
    BAl[nt] = *(const short8v*)(bl + nt*128);
  }

#define CONV_STEP(S, BH, BL, NBH, NBL)                                        \
  do {                                                                        \
    int sn = ((S)+1 < NS) ? (S)+1 : (S);                                      \
    _Pragma("unroll")                                                         \
    for (int nt = 0; nt < 6; ++nt){                                           \
      (NBH)[nt] = *(const short8v*)(bh + (size_t)sn*12288 + nt*128);          \
      (NBL)[nt] = *(const short8v*)(bl + (size_t)sn*12288 + nt*128);          \
    }                                                                         \
    int k_ = (S)/12, c_ = (S) - k_*12;                                        \
    int ab = a_base + k_*LDP + c_*32;                                         \
    short8v A0h = *(const short8v*)&xs_hi[ab];                                \
    short8v A0l = *(const short8v*)&xs_lo[ab];                                \
    short8v A1h = *(const short8v*)&xs_hi[ab + 16*LDP];                       \
    short8v A1l = *(const short8v*)&xs_lo[ab + 16*LDP];                       \
    _Pragma("unroll")                                                         \
    for (int nt = 0; nt < 6; ++nt){                                           \
      acc[0][nt] = __builtin_amdgcn_mfma_f32_16x16x32_bf16(A0h, (BH)[nt], acc[0][nt], 0,0,0); \
      acc[1][nt] = __builtin_amdgcn_mfma_f32_16x16x32_bf16(A1h, (BH)[nt], acc[1][nt], 0,0,0); \
    }                                                                         \
    _Pragma("unroll")                                                         \
    for (int nt = 0; nt < 6; ++nt){                                           \
      acc[0][nt] = __builtin_amdgcn_mfma_f32_16x16x32_bf16(A0h, (BL)[nt], acc[0][nt], 0,0,0); \
      acc[1][nt] = __builtin_amdgcn_mfma_f32_16x16x32_bf16(A1h, (BL)[nt], acc[1][nt], 0,0,0); \
    }                                                                         \
    _Pragma("unroll")                                                         \
    for (int nt = 0; nt < 6; ++nt){                                           \
      acc[0][nt] = __builtin_amdgcn_mfma_f32_16x16x32_bf16(A0l, (BH)[nt], acc[0][nt], 0,0,0); \
      acc[1][nt] = __builtin_amdgcn_mfma_f32_16x16x32_bf16(A1l, (BH)[nt], acc[1][nt], 0,0,0); \
    }                                                                         \
  } while(0)

  for (int s = 0; s < NS; s += 2){
    CONV_STEP(s,   BAh, BAl, BBh, BBl);
    CONV_STEP(s+1, BBh, BBl, BAh, BAl);
  }
#undef CONV_STEP

  // relu + LN over channels. D layout: col(o)=lane&15, row(t)=(lane>>4)*4+reg
  float gv[6], bev[6];
  #pragma unroll
  for (int nt = 0; nt < 6; ++nt){
    gv[nt]  = g[o0 + nt*16 + l15];
    bev[nt] = be[o0 + nt*16 + l15];
  }

  #pragma unroll
  for (int mt = 0; mt < 2; ++mt){
    #pragma unroll
    for (int r = 0; r < 4; ++r){
      float s1 = 0.f, s2 = 0.f;
      #pragma unroll
      for (int nt = 0; nt < 6; ++nt){
        float v = fmaxf(acc[mt][nt][r], 0.f);
        acc[mt][nt][r] = v;
        s1 += v; s2 += v*v;
      }
      s1 += __shfl_xor(s1, 1); s2 += __shfl_xor(s2, 1);
      s1 += __shfl_xor(s1, 2); s2 += __shfl_xor(s2, 2);
      s1 += __shfl_xor(s1, 4); s2 += __shfl_xor(s2, 4);
      s1 += __shfl_xor(s1, 8); s2 += __shfl_xor(s2, 8);
      if (l15 == 0){
        int t = mt*16 + lg*4 + r;
        ps[wv][t] = s1; pq[wv][t] = s2;
      }
    }
  }
  __syncthreads();

  #pragma unroll
  for (int mt = 0; mt < 2; ++mt){
    #pragma unroll
    for (int r = 0; r < 4; ++r){
      int t = mt*16 + lg*4 + r;
      float s1 = ps[0][t] + ps[1][t] + ps[2][t] + ps[3][t];
      float s2 = pq[0][t] + pq[1][t] + pq[2][t] + pq[3][t];
      float mn  = s1 * (1.f/HH);
      float var = fmaxf(s2 * (1.f/HH) - mn*mn, 0.f);
      float rr  = rsqrtf(var + 1e-5f);
      float* orow = out + ((size_t)b*T + t0 + t)*HH;
      #pragma unroll
      for (int nt = 0; nt < 6; ++nt)
        orow[o0 + nt*16 + l15] = (acc[mt][nt][r] - mn)*rr*gv[nt] + bev[nt];
    }
  }
}

// ---------------- pred = h @ lw + lb ; idx = searchsorted(bins, pred, 'left') ----
__global__ __launch_bounds__(256) void proj_var_kernel(const float* __restrict__ h,
    const float* __restrict__ lw, const float* __restrict__ lb,
    const float* __restrict__ bins, float* __restrict__ pred,
    int* __restrict__ idx, int nrows)
{
  int lane = threadIdx.x & 63, wid = threadIdx.x >> 6;
  int wave = blockIdx.x*4 + wid, nw = gridDim.x*4;
  float lwr[6];
  #pragma unroll
  for (int j = 0; j < 6; ++j) lwr[j] = lw[lane + 64*j];
  float lbv = lb[0];
  for (int row = wave; row < nrows; row += nw){
    const float* hr = h + (size_t)row*HH;
    float s = 0.f;
    #pragma unroll
    for (int j = 0; j < 6; ++j) s = fmaf(hr[lane + 64*j], lwr[j], s);
    #pragma unroll
    for (int off = 32; off; off >>= 1) s += __shfl_xor(s, off);
    if (lane == 0){
      float v = s + lbv;
      pred[row] = v;
      int lo = 0, hi = NBINS - 1;
      while (lo < hi){ int mid = (lo + hi) >> 1; if (bins[mid] < v) lo = mid + 1; else hi = mid; }
      idx[row] = lo;
    }
  }
}

// ---------------- log_d, dur (float), dur (int) ----------------
__global__ __launch_bounds__(256) void proj_dur_kernel(const float* __restrict__ h,
    const float* __restrict__ lw, const float* __restrict__ lb,
    const unsigned char* __restrict__ mask, float* __restrict__ logd,
    float* __restrict__ durf, int* __restrict__ duri, int nrows)
{
  int lane = threadIdx.x & 63, wid = threadIdx.x >> 6;
  int wave = blockIdx.x*4 + wid, nw = gridDim.x*4;
  float lwr[6];
  #pragma unroll
  for (int j = 0; j < 6; ++j) lwr[j] = lw[lane + 64*j];
  float lbv = lb[0];
  for (int row = wave; row < nrows; row += nw){
    const float* hr = h + (size_t)row*HH;
    float s = 0.f;
    #pragma unroll
    for (int j = 0; j < 6; ++j) s = fmaf(hr[lane + 64*j], lwr[j], s);
    #pragma unroll
    for (int off = 32; off; off >>= 1) s += __shfl_xor(s, off);
    if (lane == 0){
      float v = s + lbv;
      if (mask[row]) v = 0.f;
      logd[row] = v;
      float d = fmaxf(rintf(expf(v) - 1.f), 0.f);
      durf[row] = d;
      duri[row] = (int)d;
    }
  }
}

// ---------------- per-batch inclusive cumsum of dur, mel_len ----------------
__global__ __launch_bounds__(1024) void cumsum_kernel(const int* __restrict__ duri,
    int* __restrict__ cum, float* __restrict__ mel, int T, int ML)
{
  __shared__ int s[1024];
  int b = blockIdx.x, tid = threadIdx.x;
  s[tid] = (tid < T) ? duri[(size_t)b*T + tid] : 0;
  __syncthreads();
  for (int off = 1; off < 1024; off <<= 1){
    int add = (tid >= off) ? s[tid-off] : 0;
    __syncthreads();
    s[tid] += add;
    __syncthreads();
  }
  if (tid < T) cum[(size_t)b*T + tid] = s[tid];
  if (tid == T-1) mel[b] = (float)min(s[tid], ML);
}

// ---------------- x_adapt = x + pitch_table[ip] + energy_table[ie] ----------------
__global__ __launch_bounds__(256) void xadapt_kernel(const float* __restrict__ x,
    const int* __restrict__ ip, const int* __restrict__ ie,
    const float* __restrict__ pt, const float* __restrict__ et,
    float* __restrict__ xa, int nrows)
{
  int gid = blockIdx.x*256 + threadIdx.x;
  int n4 = nrows * (HH/4);
  if (gid >= n4) return;
  int row = gid / (HH/4);
  int c = gid - row*(HH/4);
  float4 xv = ((const float4*)x)[gid];
  const float4* pr = (const float4*)(pt + (size_t)ip[row]*HH);
  const float4* er = (const float4*)(et + (size_t)ie[row]*HH);
  float4 pv = pr[c], ev = er[c];
  ((float4*)xa)[gid] = make_float4(xv.x+pv.x+ev.x, xv.y+pv.y+ev.y,
                                   xv.z+pv.z+ev.z, xv.w+pv.w+ev.w);
}

// ---------------- length regulate: gather + zero-fill ----------------
__global__ __launch_bounds__(256) void lr_kernel(const float* __restrict__ xa,
    const int* __restrict__ cum, float* __restrict__ out, int T, int ML)
{
  constexpr int FR = 32;
  __shared__ int scum[1024];
  __shared__ int sidx[FR];
  __shared__ int svalid[FR];
  int b  = blockIdx.y;
  int f0 = blockIdx.x * FR;
  for (int i = threadIdx.x; i < T; i += 256) scum[i] = cum[(size_t)b*T + i];
  __syncthreads();
  int total = scum[T-1];
  if (threadIdx.x < FR){
    int f = f0 + threadIdx.x;
    int lo = 0, hi = T;
    while (lo < hi){ int mid = (lo + hi) >> 1; if (scum[mid] <= f) lo = mid + 1; else hi = mid; }
    sidx[threadIdx.x] = min(lo, T-1);
    svalid[threadIdx.x] = (f < total) ? 1 : 0;
  }
  __syncthreads();
  #pragma unroll
  for (int it = 0; it < FR*(HH/4)/256; ++it){
    int item = it*256 + threadIdx.x;
    int fl = item / (HH/4);
    int c  = item - fl*(HH/4);
    int f  = f0 + fl;
    if (f >= ML) continue;
    float4 v = make_float4(0.f,0.f,0.f,0.f);
    if (svalid[fl]) v = ((const float4*)(xa + ((size_t)b*T + sidx[fl])*HH))[c];
    ((float4*)(out + ((size_t)b*ML + f)*HH))[c] = v;
  }
}

extern "C" void kernel_launch(void* const* d_in, const int* in_sizes, int n_in,
                              void* d_out, int out_size, void* d_ws, size_t ws_size,
                              hipStream_t stream)
{
  const float* x        = (const float*)d_in[0];
  const unsigned char* src_mask = (const unsigned char*)d_in[2];
  const float* dp_w1 = (const float*)d_in[4];
  const float* dp_b1 = (const float*)d_in[5];
  const float* dp_g1 = (const float*)d_in[6];
  const float* dp_be1= (const float*)d_in[7];
  const float* dp_w2 = (const float*)d_in[8];
  const float* dp_b2 = (const float*)d_in[9];
  const float* dp_g2 = (const float*)d_in[10];
  const float* dp_be2= (const float*)d_in[11];
  const float* dp_lw = (const float*)d_in[12];
  const float* dp_lb = (const float*)d_in[13];
  const float* pp_cw = (const float*)d_in[14];
  const float* pp_cb = (const float*)d_in[15];
  const float* pp_g  = (const float*)d_in[16];
  const float* pp_b  = (const float*)d_in[17];
  const float* pp_lw = (const float*)d_in[18];
  const float* pp_lb = (const float*)d_in[19];
  const float* pp_alpha = (const float*)d_in[20];
  const float* ep_cw = (const float*)d_in[21];
  const float* ep_cb = (const float*)d_in[22];
  const float* ep_g  = (const float*)d_in[23];
  const float* ep_b  = (const float*)d_in[24];
  const float* ep_lw = (const float*)d_in[25];
  const float* ep_lb = (const float*)d_in[26];
  const float* ep_alpha = (const float*)d_in[27];
  const float* pbins = (const float*)d_in[28];
  const float* ebins = (const float*)d_in[29];
  const float* ptab  = (const float*)d_in[30];
  const float* etab  = (const float*)d_in[31];

  int B = in_sizes[1];
  int T = in_sizes[0] / (B*HH);
  int ML = (int)(((long long)out_size - B - 4LL*B*T) / ((long long)B*HH));
  size_t rows = (size_t)B*T;

  float* bufA = (float*)d_ws;
  float* bufB = bufA + rows*HH;
  int* pos    = (int*)(bufB + rows*HH);
  int* idx_p  = pos + rows;
  int* idx_e  = idx_p + rows;
  int* dur_i  = idx_e + rows;
  int* cum    = dur_i + rows;

  float* out0    = (float*)d_out;
  float* logd    = out0 + (size_t)B*ML*HH;
  float* durf    = logd + rows;
  float* pitchp  = durf + rows;
  float* energyp = pitchp + rows;
  float* mel     = energyp + rows;

  // Transformed-weight scratch lives in the out0 gather region (201 MB);
  // lr_kernel fully overwrites it at the end of every call. ~24 MB used.
  unsigned short* wsc = (unsigned short*)d_out;
  const size_t K5S = (size_t)60*12288;
  const size_t K3S = (size_t)36*12288;
  size_t woff = 0;
  unsigned short *pph[5], *ppl[5], *eph[2], *epl[2], *dph[2], *dpl[2];
  for (int l = 0; l < 5; ++l){ pph[l] = wsc + woff; woff += K5S; ppl[l] = wsc + woff; woff += K5S; }
  for (int l = 0; l < 2; ++l){ eph[l] = wsc + woff; woff += K5S; epl[l] = wsc + woff; woff += K5S; }
  for (int l = 0; l < 2; ++l){ dph[l] = wsc + woff; woff += K3S; dpl[l] = wsc + woff; woff += K3S; }

  int wt_grid = (384*384 + 255)/256;
  for (int l = 0; l < 5; ++l)
    wtrans_kernel<5><<<wt_grid, 256, 0, stream>>>(pp_cw + (size_t)l*HH*HH*5, pph[l], ppl[l]);
  for (int l = 0; l < 2; ++l)
    wtrans_kernel<5><<<wt_grid, 256, 0, stream>>>(ep_cw + (size_t)l*HH*HH*5, eph[l], epl[l]);
  wtrans_kernel<3><<<wt_grid, 256, 0, stream>>>(dp_w1, dph[0], dpl[0]);
  wtrans_kernel<3><<<wt_grid, 256, 0, stream>>>(dp_w2, dph[1], dpl[1]);

  int conv_grid = B * (T / 32);

  pos_kernel<<<B, 1024, 0, stream>>>(x, pos, T);

  // ---- pitch predictor: 5 conv layers (k=5, MFMA) ----
  add_pe_kernel<<<(int)rows, HH, 0, stream>>>(x, pos, pp_alpha, bufA);
  {
    float* src = bufA; float* dst = bufB;
    for (int l = 0; l < 5; ++l){
      conv_mfma_kernel<5><<<conv_grid, 256, 0, stream>>>(src, pph[l], ppl[l],
          pp_cb + (size_t)l*HH, pp_g + (size_t)l*HH, pp_b + (size_t)l*HH, dst, T);
      float* t2 = dst; dst = src; src = t2;
    }
    proj_var_kernel<<<256, 256, 0, stream>>>(src, pp_lw, pp_lb, pbins,
                                             pitchp, idx_p, (int)rows);
  }

  // ---- energy predictor: 2 conv layers (k=5, MFMA) ----
  add_pe_kernel<<<(int)rows, HH, 0, stream>>>(x, pos, ep_alpha, bufA);
  {
    float* src = bufA; float* dst = bufB;
    for (int l = 0; l < 2; ++l){
      conv_mfma_kernel<5><<<conv_grid, 256, 0, stream>>>(src, eph[l], epl[l],
          ep_cb + (size_t)l*HH, ep_g + (size_t)l*HH, ep_b + (size_t)l*HH, dst, T);
      float* t2 = dst; dst = src; src = t2;
    }
    proj_var_kernel<<<256, 256, 0, stream>>>(src, ep_lw, ep_lb, ebins,
                                             energyp, idx_e, (int)rows);
  }

  // ---- duration predictor: 2 conv layers (k=3, MFMA) ----
  conv_mfma_kernel<3><<<conv_grid, 256, 0, stream>>>(x, dph[0], dpl[0],
      dp_b1, dp_g1, dp_be1, bufB, T);
  conv_mfma_kernel<3><<<conv_grid, 256, 0, stream>>>(bufB, dph[1], dpl[1],
      dp_b2, dp_g2, dp_be2, bufA, T);
  proj_dur_kernel<<<256, 256, 0, stream>>>(bufA, dp_lw, dp_lb, src_mask,
                                           logd, durf, dur_i, (int)rows);

  cumsum_kernel<<<B, 1024, 0, stream>>>(dur_i, cum, mel, T, ML);

  xadapt_kernel<<<(int)((rows*(HH/4) + 255)/256), 256, 0, stream>>>(
      x, idx_p, idx_e, ptab, etab, bufB, (int)rows);

  lr_kernel<<<dim3(ML/32, B), 256, 0, stream>>>(bufB, cum, out0, T, ML);
}

// Round 5
// 1579.240 us; speedup vs baseline: 93.8769x; 1.0887x over previous
//
#include <hip/hip_runtime.h>
#include <cstdint>

#define HH 384
#define NBINS 256

typedef __attribute__((ext_vector_type(8))) short short8v;
typedef __attribute__((ext_vector_type(16))) float f32x16;
typedef __attribute__((ext_vector_type(4))) unsigned short ushort4v;

__device__ inline float4 ld4(const float* p){ return *(const float4*)p; }

__device__ inline unsigned short bf16_rne(float f){
  unsigned u = __float_as_uint(f);
  unsigned r = u + 0x7FFFu + ((u >> 16) & 1u);
  return (unsigned short)(r >> 16);
}
__device__ inline float bf16_to_f(unsigned short h){
  return __uint_as_float(((unsigned)h) << 16);
}

// ---------------- pos = cumsum(x[...,0]!=0) * mask ----------------
__global__ __launch_bounds__(1024) void pos_kernel(const float* __restrict__ x,
    int* __restrict__ pos, int T)
{
  __shared__ int s[1024];
  int b = blockIdx.x, tid = threadIdx.x;
  int m = 0;
  if (tid < T) m = (x[((size_t)b*T + tid)*HH] != 0.f) ? 1 : 0;
  s[tid] = m;
  __syncthreads();
  for (int off = 1; off < 1024; off <<= 1){
    int add = (tid >= off) ? s[tid-off] : 0;
    __syncthreads();
    s[tid] += add;
    __syncthreads();
  }
  if (tid < T) pos[(size_t)b*T + tid] = s[tid] * m;
}

// ---------------- out = x + alpha * sinusoidal_pe(pos) ----------------
__global__ __launch_bounds__(HH) void add_pe_kernel(const float* __restrict__ x,
    const int* __restrict__ pos, const float* __restrict__ alpha,
    float* __restrict__ out)
{
  int row = blockIdx.x; int i = threadIdx.x;
  int p = pos[row];
  float pe = 0.f;
  if (p != 0){
    int j = (i < HH/2) ? i : i - HH/2;
    float inv = expf((float)j * -0.04822167734018944f); // -ln(10000)/191
    float ang = (float)p * inv;
    pe = (i < HH/2) ? sinf(ang) : cosf(ang);
  }
  out[(size_t)row*HH + i] = x[(size_t)row*HH + i] + alpha[0]*pe;
}

// ---------------- weight transform: w[o][i][k] f32 -> B-frag bf16 hi/lo ------
// 32x32x16 B layout: lane l: col n = l&31, k = (l>>5)*8 + j.
// kk = k_tap*384 + ch; step s (16 kks) = k_tap*24 + (ch>>4).
// Storage: [s][half(2)][o(384)][jj(8)]  -> lane-contig 16B chunks per (s,o,half)
template<int K>
__global__ __launch_bounds__(256) void wtrans_kernel(const float* __restrict__ w,
    unsigned short* __restrict__ whi, unsigned short* __restrict__ wlo)
{
  int gid = blockIdx.x*256 + threadIdx.x; // over 384*384 (o,i)
  if (gid >= 384*384) return;
  int o = gid / 384, i = gid - (gid/384)*384;
  int c = i >> 4, half = (i >> 3) & 1, jj = i & 7;
  #pragma unroll
  for (int k = 0; k < K; ++k){
    float v = w[((size_t)o*384 + i)*K + k];
    unsigned short hi = bf16_rne(v);
    unsigned short lo = bf16_rne(v - bf16_to_f(hi));
    int s = k*24 + c;
    size_t dst = ((size_t)(s*2 + half)*384 + o)*8 + jj;
    whi[dst] = hi; wlo[dst] = lo;
  }
}

// ---------------- fused conv1d(same,K)+relu+LN via bf16-split 32x32x16 MFMA --
// Block: 32 timesteps x 384 out-channels, 4 waves; wave wv owns o in
// [wv*96, wv*96+96) as 3 tiles of 32. K-dim = 384*K in NS=24*K steps of 16.
// 3-term split: xh*wh + xh*wl + xl*wh. Explicit 2-deep register pipeline:
// prefetch B (global) and A (LDS) for step s+1, sched_barrier(0) pins the
// loads ahead of the MFMA cluster (compiler would otherwise sink them).
template<int K>
__global__ __launch_bounds__(256) void conv_mfma_kernel(
    const float* __restrict__ in, const unsigned short* __restrict__ whi,
    const unsigned short* __restrict__ wlo, const float* __restrict__ bias,
    const float* __restrict__ g, const float* __restrict__ be,
    float* __restrict__ out, int T)
{
  constexpr int M  = 32;
  constexpr int P  = (K-1)/2;
  constexpr int RT = M + K - 1;
  constexpr int NS = 24*K;
  constexpr int LDP = 392;   // 784B row stride: bank start = 4*row mod 32
  __shared__ unsigned short xs_hi[(RT+1)*LDP];  // +1 row: prefetch overrun pad
  __shared__ unsigned short xs_lo[(RT+1)*LDP];
  __shared__ float ps[4][M], pq[4][M];

  int ntile = T / M;
  int b  = blockIdx.x / ntile;
  int t0 = (blockIdx.x % ntile) * M;
  int tid = threadIdx.x;
  const float* inb = in + (size_t)b*T*HH;

  // ---- stage input tile (f32 -> bf16 hi/lo), vectorized ----
  {
    constexpr int TOT4 = RT*384/4;
    for (int e4 = tid; e4 < TOT4; e4 += 256){
      int r = e4 / 96, c4 = (e4 - r*96)*4;
      int t = t0 + r - P;
      float4 v = (t >= 0 && t < T) ? ld4(&inb[(size_t)t*HH + c4])
                                   : make_float4(0.f,0.f,0.f,0.f);
      float va[4] = {v.x, v.y, v.z, v.w};
      ushort4v h, l;
      #pragma unroll
      for (int q = 0; q < 4; ++q){
        unsigned short hq = bf16_rne(va[q]);
        h[q] = hq;
        l[q] = bf16_rne(va[q] - bf16_to_f(hq));
      }
      *(ushort4v*)&xs_hi[r*LDP + c4] = h;
      *(ushort4v*)&xs_lo[r*LDP + c4] = l;
    }
  }
  __syncthreads();

  int wv = tid >> 6, ln = tid & 63;
  int l31 = ln & 31, hl = ln >> 5;
  int o0 = wv * 96;

  // per-lane B base (16B chunks): (half*384 + o)*8 shorts
  const unsigned short* bhp = whi + ((size_t)hl*384 + o0 + l31)*8;
  const unsigned short* blp = wlo + ((size_t)hl*384 + o0 + l31)*8;
  // per-lane A base: row = l31 (timestep), k-chunk = hl*8
  int ab = l31*LDP + hl*8;

  f32x16 acc[3];
  #pragma unroll
  for (int nt = 0; nt < 3; ++nt){
    float bv = bias[o0 + nt*32 + l31];
    #pragma unroll
    for (int r = 0; r < 16; ++r) acc[nt][r] = bv;
  }

  short8v B0h[3], B0l[3], B1h[3], B1l[3];
  short8v A0h, A0l, A1h, A1l;

  // prologue: step 0 into set 0
  #pragma unroll
  for (int nt = 0; nt < 3; ++nt){
    B0h[nt] = *(const short8v*)(bhp + nt*256);
    B0l[nt] = *(const short8v*)(blp + nt*256);
  }
  A0h = *(const short8v*)&xs_hi[ab];
  A0l = *(const short8v*)&xs_lo[ab];

  int aoffN = ab, ccN = 0;

#define CONV_STEP(CAh, CAl, CBh, CBl, NAh, NAl, NBh, NBl)                     \
  do {                                                                        \
    bhp += 6144; blp += 6144;                                                 \
    aoffN += 16; if (++ccN == 24){ ccN = 0; aoffN += LDP - 384; }             \
    _Pragma("unroll")                                                         \
    for (int nt = 0; nt < 3; ++nt){                                           \
      (NBh)[nt] = *(const short8v*)(bhp + nt*256);                            \
      (NBl)[nt] = *(const short8v*)(blp + nt*256);                            \
    }                                                                         \
    (NAh) = *(const short8v*)&xs_hi[aoffN];                                   \
    (NAl) = *(const short8v*)&xs_lo[aoffN];                                   \
    __builtin_amdgcn_sched_barrier(0);                                        \
    __builtin_amdgcn_s_setprio(1);                                            \
    _Pragma("unroll")                                                         \
    for (int nt = 0; nt < 3; ++nt)                                            \
      acc[nt] = __builtin_amdgcn_mfma_f32_32x32x16_bf16((CAh), (CBh)[nt], acc[nt], 0,0,0); \
    _Pragma("unroll")                                                         \
    for (int nt = 0; nt < 3; ++nt)                                            \
      acc[nt] = __builtin_amdgcn_mfma_f32_32x32x16_bf16((CAh), (CBl)[nt], acc[nt], 0,0,0); \
    _Pragma("unroll")                                                         \
    for (int nt = 0; nt < 3; ++nt)                                            \
      acc[nt] = __builtin_amdgcn_mfma_f32_32x32x16_bf16((CAl), (CBh)[nt], acc[nt], 0,0,0); \
    __builtin_amdgcn_s_setprio(0);                                            \
  } while(0)

  for (int s = 0; s < NS; s += 2){
    CONV_STEP(A0h, A0l, B0h, B0l, A1h, A1l, B1h, B1l);
    CONV_STEP(A1h, A1l, B1h, B1l, A0h, A0l, B0h, B0l);
  }
#undef CONV_STEP

  // ---- relu + LN over channels ----
  // D layout (32x32): col o = o0+nt*32+(lane&31); row t = (r&3)+8*(r>>2)+4*hl
  float gv[3], bev[3];
  #pragma unroll
  for (int nt = 0; nt < 3; ++nt){
    gv[nt]  = g[o0 + nt*32 + l31];
    bev[nt] = be[o0 + nt*32 + l31];
  }

  #pragma unroll
  for (int r = 0; r < 16; ++r){
    float s1 = 0.f, s2 = 0.f;
    #pragma unroll
    for (int nt = 0; nt < 3; ++nt){
      float v = fmaxf(acc[nt][r], 0.f);
      acc[nt][r] = v;
      s1 += v; s2 += v*v;
    }
    s1 += __shfl_xor(s1, 1);  s2 += __shfl_xor(s2, 1);
    s1 += __shfl_xor(s1, 2);  s2 += __shfl_xor(s2, 2);
    s1 += __shfl_xor(s1, 4);  s2 += __shfl_xor(s2, 4);
    s1 += __shfl_xor(s1, 8);  s2 += __shfl_xor(s2, 8);
    s1 += __shfl_xor(s1, 16); s2 += __shfl_xor(s2, 16);
    if (l31 == 0){
      int t = (r&3) + 8*(r>>2) + 4*hl;
      ps[wv][t] = s1; pq[wv][t] = s2;
    }
  }
  __syncthreads();

  #pragma unroll
  for (int r = 0; r < 16; ++r){
    int t = (r&3) + 8*(r>>2) + 4*hl;
    float s1 = ps[0][t] + ps[1][t] + ps[2][t] + ps[3][t];
    float s2 = pq[0][t] + pq[1][t] + pq[2][t] + pq[3][t];
    float mn  = s1 * (1.f/HH);
    float var = fmaxf(s2 * (1.f/HH) - mn*mn, 0.f);
    float rr  = rsqrtf(var + 1e-5f);
    float* orow = out + ((size_t)b*T + t0 + t)*HH;
    #pragma unroll
    for (int nt = 0; nt < 3; ++nt)
      orow[o0 + nt*32 + l31] = (acc[nt][r] - mn)*rr*gv[nt] + bev[nt];
  }
}

// ---------------- pred = h @ lw + lb ; idx = searchsorted(bins, pred, 'left') ----
__global__ __launch_bounds__(256) void proj_var_kernel(const float* __restrict__ h,
    const float* __restrict__ lw, const float* __restrict__ lb,
    const float* __restrict__ bins, float* __restrict__ pred,
    int* __restrict__ idx, int nrows)
{
  int lane = threadIdx.x & 63, wid = threadIdx.x >> 6;
  int wave = blockIdx.x*4 + wid, nw = gridDim.x*4;
  float lwr[6];
  #pragma unroll
  for (int j = 0; j < 6; ++j) lwr[j] = lw[lane + 64*j];
  float lbv = lb[0];
  for (int row = wave; row < nrows; row += nw){
    const float* hr = h + (size_t)row*HH;
    float s = 0.f;
    #pragma unroll
    for (int j = 0; j < 6; ++j) s = fmaf(hr[lane + 64*j], lwr[j], s);
    #pragma unroll
    for (int off = 32; off; off >>= 1) s += __shfl_xor(s, off);
    if (lane == 0){
      float v = s + lbv;
      pred[row] = v;
      int lo = 0, hi = NBINS - 1;
      while (lo < hi){ int mid = (lo + hi) >> 1; if (bins[mid] < v) lo = mid + 1; else hi = mid; }
      idx[row] = lo;
    }
  }
}

// ---------------- log_d, dur (float), dur (int) ----------------
__global__ __launch_bounds__(256) void proj_dur_kernel(const float* __restrict__ h,
    const float* __restrict__ lw, const float* __restrict__ lb,
    const unsigned char* __restrict__ mask, float* __restrict__ logd,
    float* __restrict__ durf, int* __restrict__ duri, int nrows)
{
  int lane = threadIdx.x & 63, wid = threadIdx.x >> 6;
  int wave = blockIdx.x*4 + wid, nw = gridDim.x*4;
  float lwr[6];
  #pragma unroll
  for (int j = 0; j < 6; ++j) lwr[j] = lw[lane + 64*j];
  float lbv = lb[0];
  for (int row = wave; row < nrows; row += nw){
    const float* hr = h + (size_t)row*HH;
    float s = 0.f;
    #pragma unroll
    for (int j = 0; j < 6; ++j) s = fmaf(hr[lane + 64*j], lwr[j], s);
    #pragma unroll
    for (int off = 32; off; off >>= 1) s += __shfl_xor(s, off);
    if (lane == 0){
      float v = s + lbv;
      if (mask[row]) v = 0.f;
      logd[row] = v;
      float d = fmaxf(rintf(expf(v) - 1.f), 0.f);
      durf[row] = d;
      duri[row] = (int)d;
    }
  }
}

// ---------------- per-batch inclusive cumsum of dur, mel_len ----------------
__global__ __launch_bounds__(1024) void cumsum_kernel(const int* __restrict__ duri,
    int* __restrict__ cum, float* __restrict__ mel, int T, int ML)
{
  __shared__ int s[1024];
  int b = blockIdx.x, tid = threadIdx.x;
  s[tid] = (tid < T) ? duri[(size_t)b*T + tid] : 0;
  __syncthreads();
  for (int off = 1; off < 1024; off <<= 1){
    int add = (tid >= off) ? s[tid-off] : 0;
    __syncthreads();
    s[tid] += add;
    __syncthreads();
  }
  if (tid < T) cum[(size_t)b*T + tid] = s[tid];
  if (tid == T-1) mel[b] = (float)min(s[tid], ML);
}

// ---------------- x_adapt = x + pitch_table[ip] + energy_table[ie] ----------------
__global__ __launch_bounds__(256) void xadapt_kernel(const float* __restrict__ x,
    const int* __restrict__ ip, const int* __restrict__ ie,
    const float* __restrict__ pt, const float* __restrict__ et,
    float* __restrict__ xa, int nrows)
{
  int gid = blockIdx.x*256 + threadIdx.x;
  int n4 = nrows * (HH/4);
  if (gid >= n4) return;
  int row = gid / (HH/4);
  int c = gid - row*(HH/4);
  float4 xv = ((const float4*)x)[gid];
  const float4* pr = (const float4*)(pt + (size_t)ip[row]*HH);
  const float4* er = (const float4*)(et + (size_t)ie[row]*HH);
  float4 pv = pr[c], ev = er[c];
  ((float4*)xa)[gid] = make_float4(xv.x+pv.x+ev.x, xv.y+pv.y+ev.y,
                                   xv.z+pv.z+ev.z, xv.w+pv.w+ev.w);
}

// ---------------- length regulate: gather + zero-fill ----------------
__global__ __launch_bounds__(256) void lr_kernel(const float* __restrict__ xa,
    const int* __restrict__ cum, float* __restrict__ out, int T, int ML)
{
  constexpr int FR = 32;
  __shared__ int scum[1024];
  __shared__ int sidx[FR];
  __shared__ int svalid[FR];
  int b  = blockIdx.y;
  int f0 = blockIdx.x * FR;
  for (int i = threadIdx.x; i < T; i += 256) scum[i] = cum[(size_t)b*T + i];
  __syncthreads();
  int total = scum[T-1];
  if (threadIdx.x < FR){
    int f = f0 + threadIdx.x;
    int lo = 0, hi = T;
    while (lo < hi){ int mid = (lo + hi) >> 1; if (scum[mid] <= f) lo = mid + 1; else hi = mid; }
    sidx[threadIdx.x] = min(lo, T-1);
    svalid[threadIdx.x] = (f < total) ? 1 : 0;
  }
  __syncthreads();
  #pragma unroll
  for (int it = 0; it < FR*(HH/4)/256; ++it){
    int item = it*256 + threadIdx.x;
    int fl = item / (HH/4);
    int c  = item - fl*(HH/4);
    int f  = f0 + fl;
    if (f >= ML) continue;
    float4 v = make_float4(0.f,0.f,0.f,0.f);
    if (svalid[fl]) v = ((const float4*)(xa + ((size_t)b*T + sidx[fl])*HH))[c];
    ((float4*)(out + ((size_t)b*ML + f)*HH))[c] = v;
  }
}

extern "C" void kernel_launch(void* const* d_in, const int* in_sizes, int n_in,
                              void* d_out, int out_size, void* d_ws, size_t ws_size,
                              hipStream_t stream)
{
  const float* x        = (const float*)d_in[0];
  const unsigned char* src_mask = (const unsigned char*)d_in[2];
  const float* dp_w1 = (const float*)d_in[4];
  const float* dp_b1 = (const float*)d_in[5];
  const float* dp_g1 = (const float*)d_in[6];
  const float* dp_be1= (const float*)d_in[7];
  const float* dp_w2 = (const float*)d_in[8];
  const float* dp_b2 = (const float*)d_in[9];
  const float* dp_g2 = (const float*)d_in[10];
  const float* dp_be2= (const float*)d_in[11];
  const float* dp_lw = (const float*)d_in[12];
  const float* dp_lb = (const float*)d_in[13];
  const float* pp_cw = (const float*)d_in[14];
  const float* pp_cb = (const float*)d_in[15];
  const float* pp_g  = (const float*)d_in[16];
  const float* pp_b  = (const float*)d_in[17];
  const float* pp_lw = (const float*)d_in[18];
  const float* pp_lb = (const float*)d_in[19];
  const float* pp_alpha = (const float*)d_in[20];
  const float* ep_cw = (const float*)d_in[21];
  const float* ep_cb = (const float*)d_in[22];
  const float* ep_g  = (const float*)d_in[23];
  const float* ep_b  = (const float*)d_in[24];
  const float* ep_lw = (const float*)d_in[25];
  const float* ep_lb = (const float*)d_in[26];
  const float* ep_alpha = (const float*)d_in[27];
  const float* pbins = (const float*)d_in[28];
  const float* ebins = (const float*)d_in[29];
  const float* ptab  = (const float*)d_in[30];
  const float* etab  = (const float*)d_in[31];

  int B = in_sizes[1];
  int T = in_sizes[0] / (B*HH);
  int ML = (int)(((long long)out_size - B - 4LL*B*T) / ((long long)B*HH));
  size_t rows = (size_t)B*T;

  float* bufA = (float*)d_ws;
  float* bufB = bufA + rows*HH;
  int* pos    = (int*)(bufB + rows*HH);
  int* idx_p  = pos + rows;
  int* idx_e  = idx_p + rows;
  int* dur_i  = idx_e + rows;
  int* cum    = dur_i + rows;

  float* out0    = (float*)d_out;
  float* logd    = out0 + (size_t)B*ML*HH;
  float* durf    = logd + rows;
  float* pitchp  = durf + rows;
  float* energyp = pitchp + rows;
  float* mel     = energyp + rows;

  // Transformed-weight scratch lives in the out0 gather region (201 MB);
  // lr_kernel fully overwrites it at the end of every call. ~24 MB used.
  unsigned short* wsc = (unsigned short*)d_out;
  const size_t K5S = (size_t)120*6144;  // shorts per split, k=5 (NS=120)
  const size_t K3S = (size_t)72*6144;   // shorts per split, k=3 (NS=72)
  size_t woff = 0;
  unsigned short *pph[5], *ppl[5], *eph[2], *epl[2], *dph[2], *dpl[2];
  for (int l = 0; l < 5; ++l){ pph[l] = wsc + woff; woff += K5S; ppl[l] = wsc + woff; woff += K5S; }
  for (int l = 0; l < 2; ++l){ eph[l] = wsc + woff; woff += K5S; epl[l] = wsc + woff; woff += K5S; }
  for (int l = 0; l < 2; ++l){ dph[l] = wsc + woff; woff += K3S; dpl[l] = wsc + woff; woff += K3S; }

  int wt_grid = (384*384 + 255)/256;
  for (int l = 0; l < 5; ++l)
    wtrans_kernel<5><<<wt_grid, 256, 0, stream>>>(pp_cw + (size_t)l*HH*HH*5, pph[l], ppl[l]);
  for (int l = 0; l < 2; ++l)
    wtrans_kernel<5><<<wt_grid, 256, 0, stream>>>(ep_cw + (size_t)l*HH*HH*5, eph[l], epl[l]);
  wtrans_kernel<3><<<wt_grid, 256, 0, stream>>>(dp_w1, dph[0], dpl[0]);
  wtrans_kernel<3><<<wt_grid, 256, 0, stream>>>(dp_w2, dph[1], dpl[1]);

  int conv_grid = B * (T / 32);

  pos_kernel<<<B, 1024, 0, stream>>>(x, pos, T);

  // ---- pitch predictor: 5 conv layers (k=5, MFMA) ----
  add_pe_kernel<<<(int)rows, HH, 0, stream>>>(x, pos, pp_alpha, bufA);
  {
    float* src = bufA; float* dst = bufB;
    for (int l = 0; l < 5; ++l){
      conv_mfma_kernel<5><<<conv_grid, 256, 0, stream>>>(src, pph[l], ppl[l],
          pp_cb + (size_t)l*HH, pp_g + (size_t)l*HH, pp_b + (size_t)l*HH, dst, T);
      float* t2 = dst; dst = src; src = t2;
    }
    proj_var_kernel<<<256, 256, 0, stream>>>(src, pp_lw, pp_lb, pbins,
                                             pitchp, idx_p, (int)rows);
  }

  // ---- energy predictor: 2 conv layers (k=5, MFMA) ----
  add_pe_kernel<<<(int)rows, HH, 0, stream>>>(x, pos, ep_alpha, bufA);
  {
    float* src = bufA; float* dst = bufB;
    for (int l = 0; l < 2; ++l){
      conv_mfma_kernel<5><<<conv_grid, 256, 0, stream>>>(src, eph[l], epl[l],
          ep_cb + (size_t)l*HH, ep_g + (size_t)l*HH, ep_b + (size_t)l*HH, dst, T);
      float* t2 = dst; dst = src; src = t2;
    }
    proj_var_kernel<<<256, 256, 0, stream>>>(src, ep_lw, ep_lb, ebins,
                                             energyp, idx_e, (int)rows);
  }

  // ---- duration predictor: 2 conv layers (k=3, MFMA) ----
  conv_mfma_kernel<3><<<conv_grid, 256, 0, stream>>>(x, dph[0], dpl[0],
      dp_b1, dp_g1, dp_be1, bufB, T);
  conv_mfma_kernel<3><<<conv_grid, 256, 0, stream>>>(bufB, dph[1], dpl[1],
      dp_b2, dp_g2, dp_be2, bufA, T);
  proj_dur_kernel<<<256, 256, 0, stream>>>(bufA, dp_lw, dp_lb, src_mask,
                                           logd, durf, dur_i, (int)rows);

  cumsum_kernel<<<B, 1024, 0, stream>>>(dur_i, cum, mel, T, ML);

  xadapt_kernel<<<(int)((rows*(HH/4) + 255)/256), 256, 0, stream>>>(
      x, idx_p, idx_e, ptab, etab, bufB, (int)rows);

  lr_kernel<<<dim3(ML/32, B), 256, 0, stream>>>(bufB, cum, out0, T, ML);
}